// Round 2
// baseline (299.214 us; speedup 1.0000x reference)
//
#include <hip/hip_runtime.h>
#include <hip/hip_bf16.h>

// EfficientMultiScaleROIExtractor for MI355X (gfx950)
// fm: [1,64,120,120] f32, boxes: [4096,4] f32, MLP weights f32.
// Strategy:
//  K1: transpose CHW->HWC (LDS tile) + per-block partial channel sums
//  K2: reduce partials -> global mean -> shared head once -> gh[64]
//  K3: per-box fused: 3-scale bilinear avg-pool (HWC coalesced gathers,
//      lane=channel, wave-uniform grid point) + shared heads + final head.

#define C_CH 64
#define HW 120
#define NPIX (HW * HW)          // 14400
#define NB 4                    // boxes per block in main kernel

__global__ __launch_bounds__(256) void k_transpose_mean(
    const float* __restrict__ fm, float* __restrict__ fm_t,
    float* __restrict__ partial)
{
    __shared__ float tile[64][65];
    __shared__ float pr[4][64];
    const int t  = threadIdx.x;
    const int tx = t & 63;
    const int ty = t >> 6;
    const int pix0 = blockIdx.x * 64;   // 225 blocks * 64 pixels = 14400

    #pragma unroll
    for (int k = 0; k < 16; ++k) {
        const int c = k * 4 + ty;
        tile[c][tx] = fm[c * NPIX + pix0 + tx];   // coalesced read
    }
    __syncthreads();
    #pragma unroll
    for (int k = 0; k < 16; ++k) {
        const int p = k * 4 + ty;
        fm_t[(pix0 + p) * 64 + tx] = tile[tx][p]; // coalesced write
    }
    // partial per-channel sums over this block's 64 pixels (channel = tx)
    float s = 0.f;
    #pragma unroll
    for (int k = 0; k < 16; ++k) s += tile[tx][ty * 16 + k];
    pr[ty][tx] = s;
    __syncthreads();
    if (t < 64)
        partial[blockIdx.x * 64 + t] = pr[0][t] + pr[1][t] + pr[2][t] + pr[3][t];
}

__global__ __launch_bounds__(128) void k_ghead(
    const float* __restrict__ partial,
    const float* __restrict__ w1, const float* __restrict__ b1,
    const float* __restrict__ w2, const float* __restrict__ b2,
    float* __restrict__ gh)
{
    __shared__ float g[64];
    __shared__ float h[128];
    const int t = threadIdx.x;
    if (t < 64) {
        float s = 0.f;
        for (int b = 0; b < 225; ++b) s += partial[b * 64 + t];
        g[t] = s / 14400.f;
    }
    __syncthreads();
    {
        float a = b1[t];
        #pragma unroll 8
        for (int c = 0; c < 64; ++c) a = fmaf(g[c], w1[c * 128 + t], a);
        h[t] = fmaxf(a, 0.f);
    }
    __syncthreads();
    if (t < 64) {
        float a = b2[t];
        #pragma unroll 8
        for (int k = 0; k < 128; ++k) a = fmaf(h[k], w2[k * 64 + t], a);
        gh[t] = fmaxf(a, 0.f);
    }
}

template <int R>
__device__ __forceinline__ void pool_scale(
    const float* __restrict__ fm_t,
    float cx, float cy, float bw2, float bh2,
    int c, int gq, int t,
    float* __restrict__ pooledRow, float (*pr)[64])
{
    float acc = 0.f;
    for (int p = gq; p < R * R; p += 4) {
        const int i = p / R;          // R constexpr -> magic mul
        const int j = p % R;
        const float liny = (float)(2 * i + 1) / (float)R - 1.f;
        const float linx = (float)(2 * j + 1) / (float)R - 1.f;
        const float gy = cy + bh2 * liny;
        const float gx = cx + bw2 * linx;
        const float iy = ((gy + 1.f) * 120.f - 1.f) * 0.5f;
        const float ix = ((gx + 1.f) * 120.f - 1.f) * 0.5f;
        const float y0f = floorf(iy);
        const float x0f = floorf(ix);
        const float wy = iy - y0f;
        const float wx = ix - x0f;
        const int y0 = (int)y0f;
        const int x0 = (int)x0f;
        // wave-uniform validity (all lanes share the same grid point)
        const bool vy0 = (y0 >= 0) & (y0 < HW);
        const bool vy1 = (y0 >= -1) & (y0 < HW - 1);
        const bool vx0 = (x0 >= 0) & (x0 < HW);
        const bool vx1 = (x0 >= -1) & (x0 < HW - 1);
        const float* base = fm_t + (y0 * HW + x0) * 64 + c;
        if (vy0 & vx0) acc = fmaf((1.f - wx) * (1.f - wy), base[0],        acc);
        if (vy0 & vx1) acc = fmaf(wx * (1.f - wy),         base[64],       acc);
        if (vy1 & vx0) acc = fmaf((1.f - wx) * wy,         base[HW * 64],  acc);
        if (vy1 & vx1) acc = fmaf(wx * wy,                 base[HW * 64 + 64], acc);
    }
    pr[gq][c] = acc;
    __syncthreads();
    if (t < 64)
        pooledRow[t] = (pr[0][t] + pr[1][t] + pr[2][t] + pr[3][t]) * (1.f / (float)(R * R));
    __syncthreads();
}

__global__ __launch_bounds__(256) void k_roi_main(
    const float* __restrict__ fm_t, const float* __restrict__ boxes,
    const float* __restrict__ w1, const float* __restrict__ b1,
    const float* __restrict__ w2, const float* __restrict__ b2,
    const float* __restrict__ p1, const float* __restrict__ pb1,
    const float* __restrict__ p2, const float* __restrict__ pb2,
    const float* __restrict__ gh, float* __restrict__ out, int N)
{
    __shared__ float pooled[3][64];
    __shared__ float pr[4][64];
    __shared__ float h1[3][128];
    __shared__ float cat[256];
    __shared__ float f1[128];

    const int t  = threadIdx.x;
    const int c  = t & 63;
    const int gq = t >> 6;

    for (int nb = 0; nb < NB; ++nb) {
        const int n = blockIdx.x * NB + nb;
        if (n < N) {   // block-uniform
            const float4 bx = reinterpret_cast<const float4*>(boxes)[n];
            const float x1 = bx.x / 960.f * 2.f - 1.f;
            const float y1 = bx.y / 960.f * 2.f - 1.f;
            const float x2 = bx.z / 960.f * 2.f - 1.f;
            const float y2 = bx.w / 960.f * 2.f - 1.f;
            const float cx = (x1 + x2) * 0.5f;
            const float cy = (y1 + y2) * 0.5f;
            const float bw2 = fmaxf(x2 - x1, 1e-6f) * 0.5f;
            const float bh2 = fmaxf(y2 - y1, 1e-6f) * 0.5f;

            pool_scale<3>(fm_t, cx, cy, bw2, bh2, c, gq, t, pooled[0], pr);
            pool_scale<7>(fm_t, cx, cy, bw2, bh2, c, gq, t, pooled[1], pr);
            pool_scale<11>(fm_t, cx, cy, bw2, bh2, c, gq, t, pooled[2], pr);

            // h1: 3 scales x 128 outputs = 384 dots of length 64
            for (int o = t; o < 384; o += 256) {
                const int s = o >> 7;
                const int k = o & 127;
                float a = b1[k];
                const float* col = w1 + k;
                #pragma unroll 8
                for (int cc = 0; cc < 64; ++cc) a = fmaf(pooled[s][cc], col[cc * 128], a);
                h1[s][k] = fmaxf(a, 0.f);
            }
            __syncthreads();

            // h2 -> concat[0:192], global head -> concat[192:256]
            if (t < 192) {
                const int s = t >> 6;
                const int co = t & 63;
                float a = b2[co];
                const float* col = w2 + co;
                #pragma unroll 8
                for (int k = 0; k < 128; ++k) a = fmaf(h1[s][k], col[k * 64], a);
                cat[t] = fmaxf(a, 0.f);
            } else {
                cat[t] = gh[t - 192];
            }
            __syncthreads();

            // f1: 128 dots of length 256
            if (t < 128) {
                float a = pb1[t];
                const float* col = p1 + t;
                #pragma unroll 8
                for (int q = 0; q < 256; ++q) a = fmaf(cat[q], col[q * 128], a);
                f1[t] = fmaxf(a, 0.f);
            }
            __syncthreads();

            // out: 64 dots of length 128
            if (t < 64) {
                float a = pb2[t];
                const float* col = p2 + t;
                #pragma unroll 8
                for (int k = 0; k < 128; ++k) a = fmaf(f1[k], col[k * 64], a);
                out[n * 64 + t] = fmaxf(a, 0.f);
            }
            __syncthreads();
        }
    }
}

extern "C" void kernel_launch(void* const* d_in, const int* in_sizes, int n_in,
                              void* d_out, int out_size, void* d_ws, size_t ws_size,
                              hipStream_t stream)
{
    const float* fm    = (const float*)d_in[0];
    const float* boxes = (const float*)d_in[1];
    const float* w1    = (const float*)d_in[2];
    const float* b1    = (const float*)d_in[3];
    const float* w2    = (const float*)d_in[4];
    const float* b2    = (const float*)d_in[5];
    const float* p1    = (const float*)d_in[6];
    const float* pb1   = (const float*)d_in[7];
    const float* p2    = (const float*)d_in[8];
    const float* pb2   = (const float*)d_in[9];
    float* out = (float*)d_out;

    float* ws      = (float*)d_ws;
    float* fm_t    = ws;                 // 921600 floats
    float* partial = ws + 921600;        // 225*64 = 14400 floats
    float* gh      = ws + 921600 + 14400;// 64 floats

    const int N = in_sizes[1] / 4;       // 4096

    k_transpose_mean<<<NPIX / 64, 256, 0, stream>>>(fm, fm_t, partial);
    k_ghead<<<1, 128, 0, stream>>>(partial, w1, b1, w2, b2, gh);
    const int blocks = (N + NB - 1) / NB;
    k_roi_main<<<blocks, 256, 0, stream>>>(fm_t, boxes, w1, b1, w2, b2,
                                           p1, pb1, p2, pb2, gh, out, N);
}

// Round 3
// 172.635 us; speedup vs baseline: 1.7332x; 1.7332x over previous
//
#include <hip/hip_runtime.h>
#include <hip/hip_bf16.h>

// EfficientMultiScaleROIExtractor for MI355X (gfx950)
// fm: [1,64,120,120] f32, boxes: [4096,4] f32, MLP weights f32.
//
// K1 k_transpose_mean: CHW->HWC (coalesced gathers later) + per-block channel sums
// K2 k_ghead: global mean -> shared head -> fold into f1 bias (f1pre[128])
// K3 k_pool: 1 wave = 1 box, zero barriers. Per-point {int4 offsets, float4
//            weights*1/R^2} precomputed cooperatively into LDS, then gather:
//            2 uniform LDS reads + 4 coalesced 256B loads + 4 FMA per point.
// K4 k_heads: 16 boxes/block batched GEMM chain, register-tiled, weights via
//            float4 from cache, activations in padded LDS.

#define HW 120
#define NPIX (HW * HW)   // 14400
#define TB 16            // boxes per block in k_heads

__global__ __launch_bounds__(256) void k_transpose_mean(
    const float* __restrict__ fm, float* __restrict__ fm_t,
    float* __restrict__ partial)
{
    __shared__ float tile[64][65];
    __shared__ float pr[4][64];
    const int t  = threadIdx.x;
    const int tx = t & 63;
    const int ty = t >> 6;
    const int pix0 = blockIdx.x * 64;   // 225 blocks * 64 pixels = 14400

    #pragma unroll
    for (int k = 0; k < 16; ++k) {
        const int c = k * 4 + ty;
        tile[c][tx] = fm[c * NPIX + pix0 + tx];   // coalesced read
    }
    __syncthreads();
    #pragma unroll
    for (int k = 0; k < 16; ++k) {
        const int p = k * 4 + ty;
        fm_t[(pix0 + p) * 64 + tx] = tile[tx][p]; // coalesced write
    }
    float s = 0.f;
    #pragma unroll
    for (int k = 0; k < 16; ++k) s += tile[tx][ty * 16 + k];
    pr[ty][tx] = s;
    __syncthreads();
    if (t < 64)
        partial[blockIdx.x * 64 + t] = pr[0][t] + pr[1][t] + pr[2][t] + pr[3][t];
}

__global__ __launch_bounds__(256) void k_ghead(
    const float* __restrict__ partial,
    const float* __restrict__ w1, const float* __restrict__ b1,
    const float* __restrict__ w2, const float* __restrict__ b2,
    const float* __restrict__ p1, const float* __restrict__ pb1,
    float* __restrict__ f1pre)
{
    __shared__ float pr[4][64];
    __shared__ float g[64];
    __shared__ float h[128];
    __shared__ float gh[64];
    const int t = threadIdx.x;
    const int c = t & 63, q = t >> 6;
    float s = 0.f;
    for (int b = q; b < 225; b += 4) s += partial[b * 64 + c];
    pr[q][c] = s;
    __syncthreads();
    if (t < 64) g[t] = (pr[0][t] + pr[1][t] + pr[2][t] + pr[3][t]) * (1.f / 14400.f);
    __syncthreads();
    if (t < 128) {
        float a = b1[t];
        #pragma unroll 8
        for (int cc = 0; cc < 64; ++cc) a = fmaf(g[cc], w1[cc * 128 + t], a);
        h[t] = fmaxf(a, 0.f);
    }
    __syncthreads();
    if (t < 64) {
        float a = b2[t];
        #pragma unroll 8
        for (int k = 0; k < 128; ++k) a = fmaf(h[k], w2[k * 64 + t], a);
        gh[t] = fmaxf(a, 0.f);
    }
    __syncthreads();
    if (t < 128) {
        float a = pb1[t];
        #pragma unroll 8
        for (int j = 0; j < 64; ++j) a = fmaf(gh[j], p1[(192 + j) * 128 + t], a);
        f1pre[t] = a;   // no relu here: relu happens after cat@p1 is added
    }
}

// one wave per box, no barriers (waves touch disjoint LDS; compiler inserts
// the intra-wave lgkmcnt waits for the LDS write->read dependency)
__global__ __launch_bounds__(256) void k_pool(
    const float* __restrict__ fm_t, const float* __restrict__ boxes,
    float* __restrict__ pooled, int N)
{
    __shared__ int4   offL[4][192];
    __shared__ float4 wL[4][192];
    const int t    = threadIdx.x;
    const int lane = t & 63;
    const int wid  = t >> 6;
    const int n    = blockIdx.x * 4 + wid;
    if (n >= N) return;                 // wave-uniform

    const float4 bx = reinterpret_cast<const float4*>(boxes)[n];
    const float x1 = bx.x / 960.f * 2.f - 1.f;
    const float y1 = bx.y / 960.f * 2.f - 1.f;
    const float x2 = bx.z / 960.f * 2.f - 1.f;
    const float y2 = bx.w / 960.f * 2.f - 1.f;
    const float cx  = (x1 + x2) * 0.5f;
    const float cy  = (y1 + y2) * 0.5f;
    const float bw2 = fmaxf(x2 - x1, 1e-6f) * 0.5f;
    const float bh2 = fmaxf(y2 - y1, 1e-6f) * 0.5f;

    // cooperative per-point precompute: 3 points per lane covers 179
    #pragma unroll
    for (int rep = 0; rep < 3; ++rep) {
        const int p = lane + rep * 64;
        if (p < 179) {
            int i, j; float invR;
            if (p < 9)       { const int lp = p;      invR = 1.f / 3.f;  i = lp / 3;  j = lp - i * 3;  }
            else if (p < 58) { const int lp = p - 9;  invR = 1.f / 7.f;  i = lp / 7;  j = lp - i * 7;  }
            else             { const int lp = p - 58; invR = 1.f / 11.f; i = lp / 11; j = lp - i * 11; }
            const float liny = (float)(2 * i + 1) * invR - 1.f;
            const float linx = (float)(2 * j + 1) * invR - 1.f;
            const float gy = cy + bh2 * liny;
            const float gx = cx + bw2 * linx;
            const float iy = ((gy + 1.f) * 120.f - 1.f) * 0.5f;
            const float ix = ((gx + 1.f) * 120.f - 1.f) * 0.5f;
            const float y0f = floorf(iy), x0f = floorf(ix);
            const float wy = iy - y0f,  wx = ix - x0f;
            const int y0 = (int)y0f, x0 = (int)x0f;
            const float vy0 = (y0 >= 0 && y0 < HW)      ? 1.f : 0.f;
            const float vy1 = (y0 >= -1 && y0 < HW - 1) ? 1.f : 0.f;
            const float vx0 = (x0 >= 0 && x0 < HW)      ? 1.f : 0.f;
            const float vx1 = (x0 >= -1 && x0 < HW - 1) ? 1.f : 0.f;
            const float s2 = invR * invR;      // fold the mean into the weights
            const int x0c = min(max(x0, 0), HW - 1);
            const int x1c = min(max(x0 + 1, 0), HW - 1);
            const int y0c = min(max(y0, 0), HW - 1);
            const int y1c = min(max(y0 + 1, 0), HW - 1);
            offL[wid][p] = make_int4((y0c * HW + x0c) * 64, (y0c * HW + x1c) * 64,
                                     (y1c * HW + x0c) * 64, (y1c * HW + x1c) * 64);
            wL[wid][p] = make_float4((1.f - wx) * (1.f - wy) * s2 * (vy0 * vx0),
                                     wx * (1.f - wy) * s2 * (vy0 * vx1),
                                     (1.f - wx) * wy * s2 * (vy1 * vx0),
                                     wx * wy * s2 * (vy1 * vx1));
        }
    }

    const float* lb = fm_t + lane;
    // three segments: [0,9)=3x3, [9,58)=7x7, [58,179)=11x11
    int p = 0;
    #pragma unroll
    for (int s = 0; s < 3; ++s) {
        const int pend = (s == 0) ? 9 : (s == 1 ? 58 : 179);
        float a0 = 0.f, a1 = 0.f, a2 = 0.f, a3 = 0.f;
        for (; p < pend; ++p) {
            const int4   o = offL[wid][p];
            const float4 w = wL[wid][p];
            a0 = fmaf(w.x, lb[o.x], a0);
            a1 = fmaf(w.y, lb[o.y], a1);
            a2 = fmaf(w.z, lb[o.z], a2);
            a3 = fmaf(w.w, lb[o.w], a3);
        }
        pooled[(s * N + n) * 64 + lane] = (a0 + a1) + (a2 + a3);
    }
}

__global__ __launch_bounds__(256) void k_heads(
    const float* __restrict__ pooled,   // [3][N][64]
    const float* __restrict__ w1, const float* __restrict__ b1,
    const float* __restrict__ w2, const float* __restrict__ b2,
    const float* __restrict__ p1, const float* __restrict__ f1pre,
    const float* __restrict__ p2, const float* __restrict__ pb2,
    float* __restrict__ out, int N)
{
    __shared__ float X[3][TB][68];     // padded: rows 4 banks apart
    __shared__ float Hh[TB][132];      // 132*4B = 16B-aligned rows, 4 banks apart
    __shared__ float cat[TB][196];
    __shared__ float F[TB][132];
    __shared__ float fp[128];

    const int t  = threadIdx.x;
    const int n0 = blockIdx.x * TB;

    for (int i = t; i < 3 * TB * 64; i += 256) {
        const int s = i >> 10;          // TB*64 = 1024
        const int r = i & 1023;
        const int b = r >> 6;
        const int c = r & 63;
        const int n = n0 + b;
        X[s][b][c] = (n < N) ? pooled[(s * N + n) * 64 + c] : 0.f;
    }
    if (t < 128) fp[t] = f1pre[t];
    __syncthreads();

    const int k4  = t & 31;   // L1/L3: k = 4*k4..4*k4+3
    const int g8  = t >> 5;   // 0..7 -> boxes 2g8, 2g8+1
    const int co4 = t & 15;   // L2/L4: co = 4*co4..4*co4+3
    const int g16 = t >> 4;   // 0..15 -> box g16
    const int ba = 2 * g8, bb = 2 * g8 + 1;

    #pragma unroll 1
    for (int s = 0; s < 3; ++s) {
        {   // L1: H = relu(X_s @ w1 + b1)   [16x64]@[64x128]
            const float4 bias = *reinterpret_cast<const float4*>(b1 + 4 * k4);
            float4 accA = bias, accB = bias;
            #pragma unroll 8
            for (int cc = 0; cc < 64; ++cc) {
                const float4 wv = *reinterpret_cast<const float4*>(w1 + cc * 128 + 4 * k4);
                const float xa = X[s][ba][cc], xb = X[s][bb][cc];
                accA.x = fmaf(xa, wv.x, accA.x); accA.y = fmaf(xa, wv.y, accA.y);
                accA.z = fmaf(xa, wv.z, accA.z); accA.w = fmaf(xa, wv.w, accA.w);
                accB.x = fmaf(xb, wv.x, accB.x); accB.y = fmaf(xb, wv.y, accB.y);
                accB.z = fmaf(xb, wv.z, accB.z); accB.w = fmaf(xb, wv.w, accB.w);
            }
            accA.x = fmaxf(accA.x, 0.f); accA.y = fmaxf(accA.y, 0.f);
            accA.z = fmaxf(accA.z, 0.f); accA.w = fmaxf(accA.w, 0.f);
            accB.x = fmaxf(accB.x, 0.f); accB.y = fmaxf(accB.y, 0.f);
            accB.z = fmaxf(accB.z, 0.f); accB.w = fmaxf(accB.w, 0.f);
            *reinterpret_cast<float4*>(&Hh[ba][4 * k4]) = accA;
            *reinterpret_cast<float4*>(&Hh[bb][4 * k4]) = accB;
        }
        __syncthreads();
        {   // L2: cat_s = relu(H @ w2 + b2)  [16x128]@[128x64]
            const float4 bias = *reinterpret_cast<const float4*>(b2 + 4 * co4);
            float4 acc = bias;
            #pragma unroll 8
            for (int cc = 0; cc < 128; ++cc) {
                const float4 wv = *reinterpret_cast<const float4*>(w2 + cc * 64 + 4 * co4);
                const float h = Hh[g16][cc];
                acc.x = fmaf(h, wv.x, acc.x); acc.y = fmaf(h, wv.y, acc.y);
                acc.z = fmaf(h, wv.z, acc.z); acc.w = fmaf(h, wv.w, acc.w);
            }
            acc.x = fmaxf(acc.x, 0.f); acc.y = fmaxf(acc.y, 0.f);
            acc.z = fmaxf(acc.z, 0.f); acc.w = fmaxf(acc.w, 0.f);
            *reinterpret_cast<float4*>(&cat[g16][s * 64 + 4 * co4]) = acc;
        }
        __syncthreads();   // H about to be overwritten by next scale
    }

    {   // L3: F = relu(cat @ p1[0:192,:] + f1pre)  [16x192]@[192x128]
        const float4 bias = *reinterpret_cast<const float4*>(fp + 4 * k4);
        float4 accA = bias, accB = bias;
        #pragma unroll 8
        for (int q = 0; q < 192; ++q) {
            const float4 wv = *reinterpret_cast<const float4*>(p1 + q * 128 + 4 * k4);
            const float xa = cat[ba][q], xb = cat[bb][q];
            accA.x = fmaf(xa, wv.x, accA.x); accA.y = fmaf(xa, wv.y, accA.y);
            accA.z = fmaf(xa, wv.z, accA.z); accA.w = fmaf(xa, wv.w, accA.w);
            accB.x = fmaf(xb, wv.x, accB.x); accB.y = fmaf(xb, wv.y, accB.y);
            accB.z = fmaf(xb, wv.z, accB.z); accB.w = fmaf(xb, wv.w, accB.w);
        }
        accA.x = fmaxf(accA.x, 0.f); accA.y = fmaxf(accA.y, 0.f);
        accA.z = fmaxf(accA.z, 0.f); accA.w = fmaxf(accA.w, 0.f);
        accB.x = fmaxf(accB.x, 0.f); accB.y = fmaxf(accB.y, 0.f);
        accB.z = fmaxf(accB.z, 0.f); accB.w = fmaxf(accB.w, 0.f);
        *reinterpret_cast<float4*>(&F[ba][4 * k4]) = accA;
        *reinterpret_cast<float4*>(&F[bb][4 * k4]) = accB;
    }
    __syncthreads();
    {   // L4: out = relu(F @ p2 + pb2)  [16x128]@[128x64]
        const float4 bias = *reinterpret_cast<const float4*>(pb2 + 4 * co4);
        float4 acc = bias;
        #pragma unroll 8
        for (int cc = 0; cc < 128; ++cc) {
            const float4 wv = *reinterpret_cast<const float4*>(p2 + cc * 64 + 4 * co4);
            const float f = F[g16][cc];
            acc.x = fmaf(f, wv.x, acc.x); acc.y = fmaf(f, wv.y, acc.y);
            acc.z = fmaf(f, wv.z, acc.z); acc.w = fmaf(f, wv.w, acc.w);
        }
        acc.x = fmaxf(acc.x, 0.f); acc.y = fmaxf(acc.y, 0.f);
        acc.z = fmaxf(acc.z, 0.f); acc.w = fmaxf(acc.w, 0.f);
        const int n = n0 + g16;
        if (n < N)
            *reinterpret_cast<float4*>(out + n * 64 + 4 * co4) = acc;
    }
}

extern "C" void kernel_launch(void* const* d_in, const int* in_sizes, int n_in,
                              void* d_out, int out_size, void* d_ws, size_t ws_size,
                              hipStream_t stream)
{
    const float* fm    = (const float*)d_in[0];
    const float* boxes = (const float*)d_in[1];
    const float* w1    = (const float*)d_in[2];
    const float* b1    = (const float*)d_in[3];
    const float* w2    = (const float*)d_in[4];
    const float* b2    = (const float*)d_in[5];
    const float* p1    = (const float*)d_in[6];
    const float* pb1   = (const float*)d_in[7];
    const float* p2    = (const float*)d_in[8];
    const float* pb2   = (const float*)d_in[9];
    float* out = (float*)d_out;

    const int N = in_sizes[1] / 4;       // 4096

    float* ws      = (float*)d_ws;
    float* fm_t    = ws;                         // 921600 floats
    float* partial = fm_t + 921600;              // 14400
    float* f1pre   = partial + 14400;            // 128
    float* pooled  = f1pre + 128;                // 3*N*64

    k_transpose_mean<<<NPIX / 64, 256, 0, stream>>>(fm, fm_t, partial);
    k_ghead<<<1, 256, 0, stream>>>(partial, w1, b1, w2, b2, p1, pb1, f1pre);
    k_pool<<<(N + 3) / 4, 256, 0, stream>>>(fm_t, boxes, pooled, N);
    k_heads<<<(N + TB - 1) / TB, 256, 0, stream>>>(pooled, w1, b1, w2, b2,
                                                   p1, f1pre, p2, pb2, out, N);
}

// Round 4
// 160.054 us; speedup vs baseline: 1.8695x; 1.0786x over previous
//
#include <hip/hip_runtime.h>
#include <hip/hip_bf16.h>

// EfficientMultiScaleROIExtractor for MI355X (gfx950)
// fm: [1,64,120,120] f32, boxes: [4096,4] f32, MLP weights f32.
//
// K1 k_transpose_mean: CHW->HWC + per-block channel partial sums
// K2 k_ghead: global mean -> shared head -> folded f1 bias (f1pre[128])
// K3 k_fused: 1 wave = 1 box, NO barriers, NO cross-wave LDS:
//     phase A: bilinear 3-scale avg-pool (per-point {int4 off, float4 w}
//              precomputed cooperatively in per-wave LDS; gathers are
//              coalesced 256B loads, lane = channel)
//     phase B: 4-layer MLP entirely per-wave: activations stay distributed
//              one-element-per-lane in VGPRs; broadcasts via v_readlane
//              (uniform loop index -> SGPR operand). Weight loads are
//              256B-coalesced and identical across waves -> L1/L2 hits.

#define HW 120
#define NPIX (HW * HW)   // 14400

__device__ __forceinline__ float rdlane(float v, int l) {
    return __int_as_float(__builtin_amdgcn_readlane(__float_as_int(v), l));
}

__global__ __launch_bounds__(256) void k_transpose_mean(
    const float* __restrict__ fm, float* __restrict__ fm_t,
    float* __restrict__ partial)
{
    __shared__ float tile[64][65];
    __shared__ float pr[4][64];
    const int t  = threadIdx.x;
    const int tx = t & 63;
    const int ty = t >> 6;
    const int pix0 = blockIdx.x * 64;   // 225 blocks * 64 pixels = 14400

    #pragma unroll
    for (int k = 0; k < 16; ++k) {
        const int c = k * 4 + ty;
        tile[c][tx] = fm[c * NPIX + pix0 + tx];   // coalesced read
    }
    __syncthreads();
    #pragma unroll
    for (int k = 0; k < 16; ++k) {
        const int p = k * 4 + ty;
        fm_t[(pix0 + p) * 64 + tx] = tile[tx][p]; // coalesced write
    }
    float s = 0.f;
    #pragma unroll
    for (int k = 0; k < 16; ++k) s += tile[tx][ty * 16 + k];
    pr[ty][tx] = s;
    __syncthreads();
    if (t < 64)
        partial[blockIdx.x * 64 + t] = pr[0][t] + pr[1][t] + pr[2][t] + pr[3][t];
}

__global__ __launch_bounds__(256) void k_ghead(
    const float* __restrict__ partial,
    const float* __restrict__ w1, const float* __restrict__ b1,
    const float* __restrict__ w2, const float* __restrict__ b2,
    const float* __restrict__ p1, const float* __restrict__ pb1,
    float* __restrict__ f1pre)
{
    __shared__ float pr[4][64];
    __shared__ float g[64];
    __shared__ float h[128];
    __shared__ float gh[64];
    const int t = threadIdx.x;
    const int c = t & 63, q = t >> 6;
    float s = 0.f;
    for (int b = q; b < 225; b += 4) s += partial[b * 64 + c];
    pr[q][c] = s;
    __syncthreads();
    if (t < 64) g[t] = (pr[0][t] + pr[1][t] + pr[2][t] + pr[3][t]) * (1.f / 14400.f);
    __syncthreads();
    if (t < 128) {
        float a = b1[t];
        #pragma unroll 8
        for (int cc = 0; cc < 64; ++cc) a = fmaf(g[cc], w1[cc * 128 + t], a);
        h[t] = fmaxf(a, 0.f);
    }
    __syncthreads();
    if (t < 64) {
        float a = b2[t];
        #pragma unroll 8
        for (int k = 0; k < 128; ++k) a = fmaf(h[k], w2[k * 64 + t], a);
        gh[t] = fmaxf(a, 0.f);
    }
    __syncthreads();
    if (t < 128) {
        float a = pb1[t];
        #pragma unroll 8
        for (int j = 0; j < 64; ++j) a = fmaf(gh[j], p1[(192 + j) * 128 + t], a);
        f1pre[t] = a;   // no relu: relu happens after cat@p1 contribution
    }
}

__global__ __launch_bounds__(256, 4) void k_fused(
    const float* __restrict__ fm_t, const float* __restrict__ boxes,
    const float* __restrict__ w1, const float* __restrict__ b1,
    const float* __restrict__ w2, const float* __restrict__ b2,
    const float* __restrict__ p1, const float* __restrict__ f1pre,
    const float* __restrict__ p2, const float* __restrict__ pb2,
    float* __restrict__ out, int N)
{
    __shared__ int4   offL[4][192];
    __shared__ float4 wL[4][192];
    const int t    = threadIdx.x;
    const int lane = t & 63;
    const int wid  = t >> 6;
    const int n    = blockIdx.x * 4 + wid;
    if (n >= N) return;                 // wave-uniform; no barriers anywhere

    // ---------------- phase A: 3-scale bilinear avg-pool ----------------
    const float4 bx = reinterpret_cast<const float4*>(boxes)[n];
    const float x1 = bx.x / 960.f * 2.f - 1.f;
    const float y1 = bx.y / 960.f * 2.f - 1.f;
    const float x2 = bx.z / 960.f * 2.f - 1.f;
    const float y2 = bx.w / 960.f * 2.f - 1.f;
    const float cx  = (x1 + x2) * 0.5f;
    const float cy  = (y1 + y2) * 0.5f;
    const float bw2 = fmaxf(x2 - x1, 1e-6f) * 0.5f;
    const float bh2 = fmaxf(y2 - y1, 1e-6f) * 0.5f;

    #pragma unroll
    for (int rep = 0; rep < 3; ++rep) {
        const int p = lane + rep * 64;
        if (p < 179) {
            int i, j; float invR;
            if (p < 9)       { const int lp = p;      invR = 1.f / 3.f;  i = lp / 3;  j = lp - i * 3;  }
            else if (p < 58) { const int lp = p - 9;  invR = 1.f / 7.f;  i = lp / 7;  j = lp - i * 7;  }
            else             { const int lp = p - 58; invR = 1.f / 11.f; i = lp / 11; j = lp - i * 11; }
            const float liny = (float)(2 * i + 1) * invR - 1.f;
            const float linx = (float)(2 * j + 1) * invR - 1.f;
            const float gy = cy + bh2 * liny;
            const float gx = cx + bw2 * linx;
            const float iy = ((gy + 1.f) * 120.f - 1.f) * 0.5f;
            const float ix = ((gx + 1.f) * 120.f - 1.f) * 0.5f;
            const float y0f = floorf(iy), x0f = floorf(ix);
            const float wy = iy - y0f,  wx = ix - x0f;
            const int y0 = (int)y0f, x0 = (int)x0f;
            const float vy0 = (y0 >= 0 && y0 < HW)      ? 1.f : 0.f;
            const float vy1 = (y0 >= -1 && y0 < HW - 1) ? 1.f : 0.f;
            const float vx0 = (x0 >= 0 && x0 < HW)      ? 1.f : 0.f;
            const float vx1 = (x0 >= -1 && x0 < HW - 1) ? 1.f : 0.f;
            const float s2 = invR * invR;      // fold the mean into the weights
            const int x0c = min(max(x0, 0), HW - 1);
            const int x1c = min(max(x0 + 1, 0), HW - 1);
            const int y0c = min(max(y0, 0), HW - 1);
            const int y1c = min(max(y0 + 1, 0), HW - 1);
            offL[wid][p] = make_int4((y0c * HW + x0c) * 64, (y0c * HW + x1c) * 64,
                                     (y1c * HW + x0c) * 64, (y1c * HW + x1c) * 64);
            wL[wid][p] = make_float4((1.f - wx) * (1.f - wy) * s2 * (vy0 * vx0),
                                     wx * (1.f - wy) * s2 * (vy0 * vx1),
                                     (1.f - wx) * wy * s2 * (vy1 * vx0),
                                     wx * wy * s2 * (vy1 * vx1));
        }
    }

    const float* lb = fm_t + lane;     // lane = channel
    float x0s, x1s, x2s;
    {
        float a0, a1, a2, a3;
        #define GATHER(P0, P1, DST)                                        \
        a0 = a1 = a2 = a3 = 0.f;                                           \
        _Pragma("unroll 4")                                                \
        for (int p = (P0); p < (P1); ++p) {                                \
            const int4   o = offL[wid][p];                                 \
            const float4 w = wL[wid][p];                                   \
            a0 = fmaf(w.x, lb[o.x], a0);                                   \
            a1 = fmaf(w.y, lb[o.y], a1);                                   \
            a2 = fmaf(w.z, lb[o.z], a2);                                   \
            a3 = fmaf(w.w, lb[o.w], a3);                                   \
        }                                                                  \
        DST = (a0 + a1) + (a2 + a3);
        GATHER(0, 9, x0s)
        GATHER(9, 58, x1s)
        GATHER(58, 179, x2s)
        #undef GATHER
    }

    // ---------------- phase B: per-wave MLP (readlane broadcasts) ----------------
    // L1: H_s = relu(X_s @ w1 + b1); lane holds outputs {lane, lane+64} per scale
    float h0l, h0h, h1l, h1h, h2l, h2h;
    {
        const float bl = b1[lane], bh = b1[64 + lane];
        h0l = bl; h0h = bh; h1l = bl; h1h = bh; h2l = bl; h2h = bh;
        #pragma unroll 8
        for (int cc = 0; cc < 64; ++cc) {
            const float wlo = w1[cc * 128 + lane];
            const float whi = w1[cc * 128 + 64 + lane];
            const float xa0 = rdlane(x0s, cc);
            const float xa1 = rdlane(x1s, cc);
            const float xa2 = rdlane(x2s, cc);
            h0l = fmaf(xa0, wlo, h0l); h0h = fmaf(xa0, whi, h0h);
            h1l = fmaf(xa1, wlo, h1l); h1h = fmaf(xa1, whi, h1h);
            h2l = fmaf(xa2, wlo, h2l); h2h = fmaf(xa2, whi, h2h);
        }
        h0l = fmaxf(h0l, 0.f); h0h = fmaxf(h0h, 0.f);
        h1l = fmaxf(h1l, 0.f); h1h = fmaxf(h1h, 0.f);
        h2l = fmaxf(h2l, 0.f); h2h = fmaxf(h2h, 0.f);
    }

    // L2: cat_s = relu(H_s @ w2 + b2); lane holds cat[s*64+lane]
    float c0, c1, c2;
    {
        const float bb = b2[lane];
        c0 = bb; c1 = bb; c2 = bb;
        #pragma unroll 8
        for (int cc = 0; cc < 64; ++cc) {
            const float wa = w2[cc * 64 + lane];          // rows 0..63
            const float wb = w2[(cc + 64) * 64 + lane];   // rows 64..127
            c0 = fmaf(rdlane(h0l, cc), wa, c0); c0 = fmaf(rdlane(h0h, cc), wb, c0);
            c1 = fmaf(rdlane(h1l, cc), wa, c1); c1 = fmaf(rdlane(h1h, cc), wb, c1);
            c2 = fmaf(rdlane(h2l, cc), wa, c2); c2 = fmaf(rdlane(h2h, cc), wb, c2);
        }
        c0 = fmaxf(c0, 0.f); c1 = fmaxf(c1, 0.f); c2 = fmaxf(c2, 0.f);
    }

    // L3: F = relu(cat @ p1[0:192,:] + f1pre); lane holds {lane, lane+64}
    float flo = f1pre[lane], fhi = f1pre[64 + lane];
    {
        #define L3SEG(S, CREG)                                             \
        _Pragma("unroll 8")                                                \
        for (int j = 0; j < 64; ++j) {                                     \
            const int q = (S) * 64 + j;                                    \
            const float wlo = p1[q * 128 + lane];                          \
            const float whi = p1[q * 128 + 64 + lane];                     \
            const float xa = rdlane(CREG, j);                              \
            flo = fmaf(xa, wlo, flo); fhi = fmaf(xa, whi, fhi);            \
        }
        L3SEG(0, c0)
        L3SEG(1, c1)
        L3SEG(2, c2)
        #undef L3SEG
        flo = fmaxf(flo, 0.f); fhi = fmaxf(fhi, 0.f);
    }

    // L4: out = relu(F @ p2 + pb2); lane holds out[lane]
    {
        float o = pb2[lane];
        #pragma unroll 8
        for (int j = 0; j < 64; ++j) {
            const float wa = p2[j * 64 + lane];
            const float wb = p2[(j + 64) * 64 + lane];
            o = fmaf(rdlane(flo, j), wa, o);
            o = fmaf(rdlane(fhi, j), wb, o);
        }
        out[n * 64 + lane] = fmaxf(o, 0.f);
    }
}

extern "C" void kernel_launch(void* const* d_in, const int* in_sizes, int n_in,
                              void* d_out, int out_size, void* d_ws, size_t ws_size,
                              hipStream_t stream)
{
    const float* fm    = (const float*)d_in[0];
    const float* boxes = (const float*)d_in[1];
    const float* w1    = (const float*)d_in[2];
    const float* b1    = (const float*)d_in[3];
    const float* w2    = (const float*)d_in[4];
    const float* b2    = (const float*)d_in[5];
    const float* p1    = (const float*)d_in[6];
    const float* pb1   = (const float*)d_in[7];
    const float* p2    = (const float*)d_in[8];
    const float* pb2   = (const float*)d_in[9];
    float* out = (float*)d_out;

    const int N = in_sizes[1] / 4;       // 4096

    float* ws      = (float*)d_ws;
    float* fm_t    = ws;                         // 921600 floats
    float* partial = fm_t + 921600;              // 14400
    float* f1pre   = partial + 14400;            // 128

    k_transpose_mean<<<NPIX / 64, 256, 0, stream>>>(fm, fm_t, partial);
    k_ghead<<<1, 256, 0, stream>>>(partial, w1, b1, w2, b2, p1, pb1, f1pre);
    k_fused<<<(N + 3) / 4, 256, 0, stream>>>(fm_t, boxes, w1, b1, w2, b2,
                                             p1, f1pre, p2, pb2, out, N);
}

// Round 5
// 150.043 us; speedup vs baseline: 1.9942x; 1.0667x over previous
//
#include <hip/hip_runtime.h>
#include <hip/hip_bf16.h>

// EfficientMultiScaleROIExtractor for MI355X (gfx950)
// fm: [1,64,120,120] f32, boxes: [4096,4] f32, MLP weights f32.
//
// K1 k_transpose_mean: CHW->HWC + per-block channel partial sums
// K2 k_ghead: global mean -> shared head -> folded f1 bias (f1pre[128])
// K3 k_fused: 1 wave = 1 box, no barriers, no cross-wave LDS:
//   phase A (pool): lane = (pg=point-group, qc=channel-quad). Each VMEM
//     instruction fetches one corner for 4 points (16 lanes x float4 =
//     64 channels = 1KB coalesced). Byte offsets/weights precomputed
//     cooperatively in per-wave LDS. Cross-group combine via shfl_xor.
//   phase B (MLP): activations broadcast via uniform-address ds_read_b128
//     from per-wave LDS (no readlane storm, no barriers); weights are
//     256B-coalesced loads identical across waves (L1/L2-served).

#define HW 120
#define NPIX (HW * HW)   // 14400

__global__ __launch_bounds__(256) void k_transpose_mean(
    const float* __restrict__ fm, float* __restrict__ fm_t,
    float* __restrict__ partial)
{
    __shared__ float tile[64][65];
    __shared__ float pr[4][64];
    const int t  = threadIdx.x;
    const int tx = t & 63;
    const int ty = t >> 6;
    const int pix0 = blockIdx.x * 64;   // 225 blocks * 64 pixels = 14400

    #pragma unroll
    for (int k = 0; k < 16; ++k) {
        const int c = k * 4 + ty;
        tile[c][tx] = fm[c * NPIX + pix0 + tx];   // coalesced read
    }
    __syncthreads();
    #pragma unroll
    for (int k = 0; k < 16; ++k) {
        const int p = k * 4 + ty;
        fm_t[(pix0 + p) * 64 + tx] = tile[tx][p]; // coalesced write
    }
    float s = 0.f;
    #pragma unroll
    for (int k = 0; k < 16; ++k) s += tile[tx][ty * 16 + k];
    pr[ty][tx] = s;
    __syncthreads();
    if (t < 64)
        partial[blockIdx.x * 64 + t] = pr[0][t] + pr[1][t] + pr[2][t] + pr[3][t];
}

__global__ __launch_bounds__(256) void k_ghead(
    const float* __restrict__ partial,
    const float* __restrict__ w1, const float* __restrict__ b1,
    const float* __restrict__ w2, const float* __restrict__ b2,
    const float* __restrict__ p1, const float* __restrict__ pb1,
    float* __restrict__ f1pre)
{
    __shared__ float pr[4][64];
    __shared__ float g[64];
    __shared__ float h[128];
    __shared__ float gh[64];
    const int t = threadIdx.x;
    const int c = t & 63, q = t >> 6;
    float s = 0.f;
    for (int b = q; b < 225; b += 4) s += partial[b * 64 + c];
    pr[q][c] = s;
    __syncthreads();
    if (t < 64) g[t] = (pr[0][t] + pr[1][t] + pr[2][t] + pr[3][t]) * (1.f / 14400.f);
    __syncthreads();
    if (t < 128) {
        float a = b1[t];
        #pragma unroll 8
        for (int cc = 0; cc < 64; ++cc) a = fmaf(g[cc], w1[cc * 128 + t], a);
        h[t] = fmaxf(a, 0.f);
    }
    __syncthreads();
    if (t < 64) {
        float a = b2[t];
        #pragma unroll 8
        for (int k = 0; k < 128; ++k) a = fmaf(h[k], w2[k * 64 + t], a);
        gh[t] = fmaxf(a, 0.f);
    }
    __syncthreads();
    if (t < 128) {
        float a = pb1[t];
        #pragma unroll 8
        for (int j = 0; j < 64; ++j) a = fmaf(gh[j], p1[(192 + j) * 128 + t], a);
        f1pre[t] = a;   // no relu: relu happens after cat@p1 contribution
    }
}

__device__ __forceinline__ float4 gather_seg(
    const int4* off, const float4* ww, const char* fb, int pg, int P0, int P1)
{
    float ax = 0.f, ay = 0.f, az = 0.f, aw = 0.f;
    #pragma unroll 2
    for (int p = P0 + pg; p < P1; p += 4) {
        const int4   o = off[p];
        const float4 w = ww[p];
        const float4 v0 = *(const float4*)(fb + o.x);
        const float4 v1 = *(const float4*)(fb + o.y);
        const float4 v2 = *(const float4*)(fb + o.z);
        const float4 v3 = *(const float4*)(fb + o.w);
        ax = fmaf(w.x, v0.x, ax); ay = fmaf(w.x, v0.y, ay);
        az = fmaf(w.x, v0.z, az); aw = fmaf(w.x, v0.w, aw);
        ax = fmaf(w.y, v1.x, ax); ay = fmaf(w.y, v1.y, ay);
        az = fmaf(w.y, v1.z, az); aw = fmaf(w.y, v1.w, aw);
        ax = fmaf(w.z, v2.x, ax); ay = fmaf(w.z, v2.y, ay);
        az = fmaf(w.z, v2.z, az); aw = fmaf(w.z, v2.w, aw);
        ax = fmaf(w.w, v3.x, ax); ay = fmaf(w.w, v3.y, ay);
        az = fmaf(w.w, v3.z, az); aw = fmaf(w.w, v3.w, aw);
    }
    // combine the 4 point-groups (lanes l, l^16, l^32, l^48)
    ax += __shfl_xor(ax, 16, 64); ay += __shfl_xor(ay, 16, 64);
    az += __shfl_xor(az, 16, 64); aw += __shfl_xor(aw, 16, 64);
    ax += __shfl_xor(ax, 32, 64); ay += __shfl_xor(ay, 32, 64);
    az += __shfl_xor(az, 32, 64); aw += __shfl_xor(aw, 32, 64);
    return make_float4(ax, ay, az, aw);
}

__global__ __launch_bounds__(256) void k_fused(
    const float* __restrict__ fm_t, const float* __restrict__ boxes,
    const float* __restrict__ w1, const float* __restrict__ b1,
    const float* __restrict__ w2, const float* __restrict__ b2,
    const float* __restrict__ p1, const float* __restrict__ f1pre,
    const float* __restrict__ p2, const float* __restrict__ pb2,
    float* __restrict__ out, int N)
{
    __shared__ __align__(16) int4   offS[4][192];
    __shared__ __align__(16) float4 wS[4][192];
    __shared__ __align__(16) float  xbufS[4][192];   // [3][64] per wave
    __shared__ __align__(16) float  hbufS[4][384];   // [3][128] per wave
    __shared__ __align__(16) float  cbufS[4][192];
    __shared__ __align__(16) float  fbufS[4][128];

    const int t    = threadIdx.x;
    const int lane = t & 63;
    const int wid  = t >> 6;
    const int n    = blockIdx.x * 4 + wid;
    if (n >= N) return;                 // wave-uniform; no barriers anywhere

    const int4*   off  = offS[wid];
    const float4* ww   = wS[wid];
    float* xbuf = xbufS[wid];
    float* hbuf = hbufS[wid];
    float* cbuf = cbufS[wid];
    float* fbuf = fbufS[wid];

    // ---------------- phase A0: per-point tables ----------------
    const float4 bx = reinterpret_cast<const float4*>(boxes)[n];
    const float x1 = bx.x / 960.f * 2.f - 1.f;
    const float y1 = bx.y / 960.f * 2.f - 1.f;
    const float x2 = bx.z / 960.f * 2.f - 1.f;
    const float y2 = bx.w / 960.f * 2.f - 1.f;
    const float cx  = (x1 + x2) * 0.5f;
    const float cy  = (y1 + y2) * 0.5f;
    const float bw2 = fmaxf(x2 - x1, 1e-6f) * 0.5f;
    const float bh2 = fmaxf(y2 - y1, 1e-6f) * 0.5f;

    #pragma unroll
    for (int rep = 0; rep < 3; ++rep) {
        const int p = lane + rep * 64;
        if (p < 179) {
            int i, j; float invR;
            if (p < 9)       { const int lp = p;      invR = 1.f / 3.f;  i = lp / 3;  j = lp - i * 3;  }
            else if (p < 58) { const int lp = p - 9;  invR = 1.f / 7.f;  i = lp / 7;  j = lp - i * 7;  }
            else             { const int lp = p - 58; invR = 1.f / 11.f; i = lp / 11; j = lp - i * 11; }
            const float liny = (float)(2 * i + 1) * invR - 1.f;
            const float linx = (float)(2 * j + 1) * invR - 1.f;
            const float gy = cy + bh2 * liny;
            const float gx = cx + bw2 * linx;
            const float iy = ((gy + 1.f) * 120.f - 1.f) * 0.5f;
            const float ix = ((gx + 1.f) * 120.f - 1.f) * 0.5f;
            const float y0f = floorf(iy), x0f = floorf(ix);
            const float wy = iy - y0f,  wx = ix - x0f;
            const int y0 = (int)y0f, x0 = (int)x0f;
            const float vy0 = (y0 >= 0 && y0 < HW)      ? 1.f : 0.f;
            const float vy1 = (y0 >= -1 && y0 < HW - 1) ? 1.f : 0.f;
            const float vx0 = (x0 >= 0 && x0 < HW)      ? 1.f : 0.f;
            const float vx1 = (x0 >= -1 && x0 < HW - 1) ? 1.f : 0.f;
            const float s2 = invR * invR;      // fold the mean into the weights
            const int x0c = min(max(x0, 0), HW - 1);
            const int x1c = min(max(x0 + 1, 0), HW - 1);
            const int y0c = min(max(y0, 0), HW - 1);
            const int y1c = min(max(y0 + 1, 0), HW - 1);
            // byte offsets: one HWC pixel = 64 ch * 4B = 256B
            offS[wid][p] = make_int4((y0c * HW + x0c) * 256, (y0c * HW + x1c) * 256,
                                     (y1c * HW + x0c) * 256, (y1c * HW + x1c) * 256);
            wS[wid][p] = make_float4((1.f - wx) * (1.f - wy) * s2 * (vy0 * vx0),
                                     wx * (1.f - wy) * s2 * (vy0 * vx1),
                                     (1.f - wx) * wy * s2 * (vy1 * vx0),
                                     wx * wy * s2 * (vy1 * vx1));
        }
    }

    // ---------------- phase A1: gather (4 points in parallel) ----------------
    const int qc = lane & 15;           // channel quad: channels 4qc..4qc+3
    const int pg = lane >> 4;           // point group 0..3
    const char* fb = (const char*)fm_t + qc * 16;

    const float4 r0 = gather_seg(off, ww, fb, pg, 0, 9);     // 3x3
    const float4 r1 = gather_seg(off, ww, fb, pg, 9, 58);    // 7x7
    const float4 r2 = gather_seg(off, ww, fb, pg, 58, 179);  // 11x11
    if (pg == 0) {
        *(float4*)(xbuf +       4 * qc) = r0;
        *(float4*)(xbuf +  64 + 4 * qc) = r1;
        *(float4*)(xbuf + 128 + 4 * qc) = r2;
    }

    // ---------------- phase B: per-wave MLP (LDS uniform broadcasts) ----------------
    // L1: H_s = relu(X_s @ w1 + b1); lane holds outputs {lane, lane+64}
    float h0l, h0h, h1l, h1h, h2l, h2h;
    {
        const float bl = b1[lane], bh = b1[64 + lane];
        h0l = h1l = h2l = bl; h0h = h1h = h2h = bh;
        #define L1STEP(XA0, XA1, XA2, CC) {                                \
            const float wlo = w1[(CC) * 128 + lane];                       \
            const float whi = w1[(CC) * 128 + 64 + lane];                  \
            h0l = fmaf(XA0, wlo, h0l); h0h = fmaf(XA0, whi, h0h);          \
            h1l = fmaf(XA1, wlo, h1l); h1h = fmaf(XA1, whi, h1h);          \
            h2l = fmaf(XA2, wlo, h2l); h2h = fmaf(XA2, whi, h2h); }
        #pragma unroll 4
        for (int k4 = 0; k4 < 16; ++k4) {
            const float4 xv0 = *(const float4*)(xbuf +       4 * k4); // uniform -> broadcast
            const float4 xv1 = *(const float4*)(xbuf +  64 + 4 * k4);
            const float4 xv2 = *(const float4*)(xbuf + 128 + 4 * k4);
            L1STEP(xv0.x, xv1.x, xv2.x, 4 * k4 + 0)
            L1STEP(xv0.y, xv1.y, xv2.y, 4 * k4 + 1)
            L1STEP(xv0.z, xv1.z, xv2.z, 4 * k4 + 2)
            L1STEP(xv0.w, xv1.w, xv2.w, 4 * k4 + 3)
        }
        #undef L1STEP
        h0l = fmaxf(h0l, 0.f); h0h = fmaxf(h0h, 0.f);
        h1l = fmaxf(h1l, 0.f); h1h = fmaxf(h1h, 0.f);
        h2l = fmaxf(h2l, 0.f); h2h = fmaxf(h2h, 0.f);
        hbuf[lane]       = h0l; hbuf[64 + lane]  = h0h;
        hbuf[128 + lane] = h1l; hbuf[192 + lane] = h1h;
        hbuf[256 + lane] = h2l; hbuf[320 + lane] = h2h;
    }

    // L2: cat_s = relu(H_s @ w2 + b2); lane holds cat[s*64+lane]
    {
        const float bb = b2[lane];
        float c0 = bb, c1 = bb, c2 = bb;
        #define L2STEP(HA0, HA1, HA2, CC) {                                \
            const float wa = w2[(CC) * 64 + lane];                         \
            c0 = fmaf(HA0, wa, c0);                                        \
            c1 = fmaf(HA1, wa, c1);                                        \
            c2 = fmaf(HA2, wa, c2); }
        #pragma unroll 4
        for (int k4 = 0; k4 < 32; ++k4) {
            const float4 hv0 = *(const float4*)(hbuf +       4 * k4);
            const float4 hv1 = *(const float4*)(hbuf + 128 + 4 * k4);
            const float4 hv2 = *(const float4*)(hbuf + 256 + 4 * k4);
            L2STEP(hv0.x, hv1.x, hv2.x, 4 * k4 + 0)
            L2STEP(hv0.y, hv1.y, hv2.y, 4 * k4 + 1)
            L2STEP(hv0.z, hv1.z, hv2.z, 4 * k4 + 2)
            L2STEP(hv0.w, hv1.w, hv2.w, 4 * k4 + 3)
        }
        #undef L2STEP
        cbuf[lane]       = fmaxf(c0, 0.f);
        cbuf[64 + lane]  = fmaxf(c1, 0.f);
        cbuf[128 + lane] = fmaxf(c2, 0.f);
    }

    // L3: F = relu(cat @ p1[0:192,:] + f1pre); lane holds {lane, lane+64}
    {
        float flo = f1pre[lane], fhi = f1pre[64 + lane];
        #define L3STEP(CA, QQ) {                                           \
            const float wlo = p1[(QQ) * 128 + lane];                       \
            const float whi = p1[(QQ) * 128 + 64 + lane];                  \
            flo = fmaf(CA, wlo, flo); fhi = fmaf(CA, whi, fhi); }
        #pragma unroll 4
        for (int q4 = 0; q4 < 48; ++q4) {
            const float4 cv = *(const float4*)(cbuf + 4 * q4);
            L3STEP(cv.x, 4 * q4 + 0)
            L3STEP(cv.y, 4 * q4 + 1)
            L3STEP(cv.z, 4 * q4 + 2)
            L3STEP(cv.w, 4 * q4 + 3)
        }
        #undef L3STEP
        fbuf[lane]      = fmaxf(flo, 0.f);
        fbuf[64 + lane] = fmaxf(fhi, 0.f);
    }

    // L4: out = relu(F @ p2 + pb2); lane holds out[lane]
    {
        float o = pb2[lane];
        #define L4STEP(FA, JJ) o = fmaf(FA, p2[(JJ) * 64 + lane], o);
        #pragma unroll 4
        for (int j4 = 0; j4 < 32; ++j4) {
            const float4 fv = *(const float4*)(fbuf + 4 * j4);
            L4STEP(fv.x, 4 * j4 + 0)
            L4STEP(fv.y, 4 * j4 + 1)
            L4STEP(fv.z, 4 * j4 + 2)
            L4STEP(fv.w, 4 * j4 + 3)
        }
        #undef L4STEP
        out[n * 64 + lane] = fmaxf(o, 0.f);
    }
}

extern "C" void kernel_launch(void* const* d_in, const int* in_sizes, int n_in,
                              void* d_out, int out_size, void* d_ws, size_t ws_size,
                              hipStream_t stream)
{
    const float* fm    = (const float*)d_in[0];
    const float* boxes = (const float*)d_in[1];
    const float* w1    = (const float*)d_in[2];
    const float* b1    = (const float*)d_in[3];
    const float* w2    = (const float*)d_in[4];
    const float* b2    = (const float*)d_in[5];
    const float* p1    = (const float*)d_in[6];
    const float* pb1   = (const float*)d_in[7];
    const float* p2    = (const float*)d_in[8];
    const float* pb2   = (const float*)d_in[9];
    float* out = (float*)d_out;

    const int N = in_sizes[1] / 4;       // 4096

    float* ws      = (float*)d_ws;
    float* fm_t    = ws;                         // 921600 floats
    float* partial = fm_t + 921600;              // 14400
    float* f1pre   = partial + 14400;            // 128

    k_transpose_mean<<<NPIX / 64, 256, 0, stream>>>(fm, fm_t, partial);
    k_ghead<<<1, 256, 0, stream>>>(partial, w1, b1, w2, b2, p1, pb1, f1pre);
    k_fused<<<(N + 3) / 4, 256, 0, stream>>>(fm_t, boxes, w1, b1, w2, b2,
                                             p1, f1pre, p2, pb2, out, N);
}